// Round 1
// baseline (533.605 us; speedup 1.0000x reference)
//
#include <hip/hip_runtime.h>

// RelativePositionEncoding (AF3-style), B=1, N=1024, C_Z=128. HBM-write-bound:
// 537 MB out, write roofline ~85 us @ 6.3 TB/s. Harness adds ~425 us/iter of
// poison-fill overhead (2 GiB d_ws + 537 MB d_out) visible in rocprof.
//
// R6: split-table gather. R5 fused all three terms into one 792-row (405 KB)
// table; random sym_id makes crow vary per-j, so far-field gathers walk a
// ~50-150 KB per-i working set (> 32 KB L1) with a fresh row per j. Split:
//   Pos[132][128] (67.6 KB, ws): row<66: W_pos[32]+W_tok[row] (same chain+res)
//                                row>=66: W_pos[row-66]+W_tok[65]
//   Ch[6][128]    (3 KB, LDS):   c<5: W_ch[c]+w_ent (same ent); c=5: W_ch[5]
// Gather address now depends only on `row` -> constant over chain-runs of j
// (L1-hit broadcast); ch term comes from LDS (conflict-free b128 broadcast)
// and is added in-register. Association (Wp+Wt)+(Wch+went) matches R5 ->
// bitwise-identical output (absmax=0).
//
// nt stores kept from R5: the 537 MB write stream must not evict the tables.

#define RMAX 32
#define SMAX 2
#define TJ 512
#define BLOCK 256

typedef float v4f __attribute__((ext_vector_type(4)));

// ---- K1: build Pos[132][128] then Ch[6][128] contiguously in d_ws ----
__global__ __launch_bounds__(BLOCK) void build_tables(
    const float* __restrict__ W, v4f* __restrict__ T)
{
    const int t = blockIdx.x * BLOCK + threadIdx.x;
    if (t >= 138 * 32) return;
    const int rc = t >> 5;          // table row 0..137 (132 Pos + 6 Ch)
    const int cc = t & 31;          // float4 group 0..31

    const v4f* __restrict__ W4 = reinterpret_cast<const v4f*>(W);
    // W rows: W_pos 0..65, W_tok 66..131, w_ent 132, W_ch 133..138.
    v4f o;
    if (rc < 66) {
        o = W4[32 * 32 + cc] + W4[(66 + rc) * 32 + cc];
    } else if (rc < 132) {
        o = W4[(rc - 66) * 32 + cc] + W4[131 * 32 + cc];
    } else {
        const int c = rc - 132;     // 0..5
        if (c < 5) o = W4[(133 + c) * 32 + cc] + W4[132 * 32 + cc];
        else       o = W4[138 * 32 + cc];
    }
    T[rc * 32 + cc] = o;
}

// ---- K2: stream the output; Pos gather (L1-run-friendly) + LDS ch add ----
__global__ __launch_bounds__(BLOCK) void relpos_stream(
    const int* __restrict__ asym, const int* __restrict__ resi,
    const int* __restrict__ ent,  const int* __restrict__ sym,
    const int* __restrict__ tok,  const char* __restrict__ Tbytes,
    float* __restrict__ out, int N)
{
    __shared__ int sAddr[TJ];       // per-j packed (row*512 | crow<<20), 2 KB
    __shared__ v4f sCh[6 * 32];     // 6 ch rows x 512 B = 3 KB

    const int tid = threadIdx.x;
    const int i   = blockIdx.y;
    const int j0  = blockIdx.x * TJ;

    // stage the 6 ch rows into LDS (Ch lives at byte 132*512 in T)
    if (tid < 192)
        sCh[tid] = *reinterpret_cast<const v4f*>(Tbytes + 132 * 512 + (tid << 4));

    // --- index build: packed offsets for this j-tile ---
    const int ai = asym[i], ri = resi[i], ei = ent[i], si = sym[i], ti = tok[i];
    for (int t = tid; t < TJ; t += BLOCK) {
        const int j = j0 + t;
        const int aj = asym[j], rj = resi[j], ej = ent[j], sj = sym[j], tj = tok[j];
        int row;
        if (ai == aj) {
            if (ri == rj) {
                int dt = ti - tj + RMAX;
                dt = dt < 0 ? 0 : (dt > 2 * RMAX ? 2 * RMAX : dt);
                row = dt;
            } else {
                int dr = ri - rj + RMAX;
                dr = dr < 0 ? 0 : (dr > 2 * RMAX ? 2 * RMAX : dr);
                row = 66 + dr;
            }
        } else {
            row = 131;
        }
        int crow;
        if (ei == ej) {
            int dc = si - sj + SMAX;
            dc = dc < 0 ? 0 : (dc > 2 * SMAX ? 2 * SMAX : dc);
            crow = dc;
        } else {
            crow = 5;
        }
        sAddr[t] = (row << 9) | (crow << 20);   // row*512 bytes | ch row id
    }
    __syncthreads();

    // --- stream: wave = 2 rows x 512 B = contiguous 1024 B nt stores ---
    const int cc = tid & 31;   // float4 group within row
    const int jl = tid >> 5;   // 0..7
    v4f* __restrict__ out4 = reinterpret_cast<v4f*>(out);
    const size_t base = ((size_t)i * N + j0) * 32 + cc;

    #pragma unroll 8
    for (int jj = jl; jj < TJ; jj += 8) {
        const int a = sAddr[jj];
        const v4f p = *reinterpret_cast<const v4f*>(
            Tbytes + (a & 0xFFFFF) + (cc << 4));
        const v4f v = p + sCh[((a >> 20) << 5) + cc];
        __builtin_nontemporal_store(v, out4 + base + (size_t)jj * 32);
    }
}

extern "C" void kernel_launch(void* const* d_in, const int* in_sizes, int n_in,
                              void* d_out, int out_size, void* d_ws, size_t ws_size,
                              hipStream_t stream) {
    const int* asym = (const int*)d_in[0];
    const int* resi = (const int*)d_in[1];
    const int* ent  = (const int*)d_in[2];
    const int* sym  = (const int*)d_in[3];
    const int* tok  = (const int*)d_in[4];
    const float* W  = (const float*)d_in[5];
    float* out = (float*)d_out;

    const int N = in_sizes[0];          // B*N with B=1 (N=1024)

    // K1: 138 rows * 32 float4 = 4416 threads -> 18 blocks
    build_tables<<<18, BLOCK, 0, stream>>>(W, (v4f*)d_ws);

    // K2: (j-tile, i) grid; same-stream ordering makes T visible to K2
    dim3 grid(N / TJ, N);
    relpos_stream<<<grid, BLOCK, 0, stream>>>(
        asym, resi, ent, sym, tok, (const char*)d_ws, out, N);
}